// Round 18
// baseline (8117.294 us; speedup 1.0000x reference)
//
#include <hip/hip_runtime.h>
#include <math.h>

// RNN with short-term plasticity: persistent cooperative kernel.
//
// Round 18: SPARSE K-SPLIT, GROUP-OF-8 PER BATCH. The 10%-dense mask lets
// a WG hold its K-slice of W as CSR in LDS (~147 KB), so member k of
// batch-group b owns BOTH state of neurons [128k,+128) AND K-slice
// j in [128k,+128): the A[j] its GEMM needs is its OWN state -> no A
// broadcast at all. Cross-WG traffic per step: 896 partial floats out,
// 896 in, one 8-stamp barrier (vs r11: 16KB A-read x32 members, 32-stamp
// barrier). Straggler-max drops from max-of-32 to max-of-8. Dropping
// mask-zero terms is exact (they contribute 0.0). Agent-scope atomics
// only (r17's sc0 experiment HUNG: repeated sc0 polls serve stale L1 --
// never spin on unverified cache semantics).
//
// Ordering proof sketch (one bar/step): publish(t) -> bar(t) -> read(t).
// Pbuf[par] writer at t+2 must pass bar(t+1), which needs every reader's
// stamp(t+1), which follows that reader's read(t). Zbuf: store(t, after
// bar(t)) -> drained by bar(t+1)'s leading syncthreads -> read after
// bar(t+1). A stays WG-local (LDS).
//
#define NH 1024
#define NB 32
#define NI 8
#define NO 8
#define TSTEPS 1000

#define NWG 256
#define BLK 512
#define NMEM 8        // members per batch-group (K-split)
#define KS 128        // neurons (and K-cols) per member
#define CAP 56        // CSR capacity per thread (2 rows; mean 25.6, 6.3 sigma)
#define CSTR 57       // padded LDS stride (odd -> no systematic bank conflicts)

#define OFF_Z 0
#define OFF_H (NB * TSTEPS * NO)            // 256000
#define OFF_R (OFF_H + NB * TSTEPS * NH)    // 33024000
#define OFF_U (OFF_R + NB * TSTEPS * NH)    // 65792000

// ws: u32 slots [NWG][32] (128B lines) = 32 KB; then floats:
#define WS_P  8192                                  // Pbuf[2][NB][dst8][src8][KS]
#define WS_Zb (WS_P + 2 * NB * NMEM * NMEM * KS)    // Zbuf[2][NB][src8][NO]

typedef unsigned long long u64;
typedef unsigned int u32;

__device__ __forceinline__ float aload1(const float* p) {
    return __hip_atomic_load(p, __ATOMIC_RELAXED, __HIP_MEMORY_SCOPE_AGENT);
}
__device__ __forceinline__ void astore(float* p, float v) {
    __hip_atomic_store(p, v, __ATOMIC_RELAXED, __HIP_MEMORY_SCOPE_AGENT);
}
__device__ __forceinline__ void astore64(u64* p, float a, float b) {
    u64 v = (u64)__builtin_bit_cast(u32, a)
          | ((u64)__builtin_bit_cast(u32, b) << 32);
    __hip_atomic_store(p, v, __ATOMIC_RELAXED, __HIP_MEMORY_SCOPE_AGENT);
}

// 8-member barrier (proven r11 protocol, smaller group). Release ordering:
// leading __syncthreads drains vmcnt in every wave (all agent stores ack'd
// at the coherence point) before thread 0 stamps.
__device__ __forceinline__ void groupbar(unsigned* slot, int b, int mem,
                                         unsigned stamp) {
    __syncthreads();
    if (threadIdx.x == 0)
        __hip_atomic_store(&slot[(b * NMEM + mem) * 32], stamp,
                           __ATOMIC_RELAXED, __HIP_MEMORY_SCOPE_AGENT);
    if (threadIdx.x < NMEM) {
        while (__hip_atomic_load(&slot[(b * NMEM + threadIdx.x) * 32],
                                 __ATOMIC_RELAXED, __HIP_MEMORY_SCOPE_AGENT)
               < stamp)
            __builtin_amdgcn_s_sleep(1);
    }
    __syncthreads();
}

__global__ __launch_bounds__(BLK, 1) void rnn_stp_kernel(
    const float* __restrict__ x,     // [32][1000][8]
    const float* __restrict__ h0,    // [32][1024]
    const float* __restrict__ r0,    // [32][1024]
    const float* __restrict__ u0,    // [32][1024]
    const float* __restrict__ prel,  // [1024]
    const float* __restrict__ scal,  // [1024]
    const float* __restrict__ Wih,   // [1024][8]
    const float* __restrict__ Whh,   // [1024][1024]
    const float* __restrict__ Wmask, // [1024][1024]
    const float* __restrict__ Whz,   // [8][1024]
    float* __restrict__ out,
    float* __restrict__ ws)
{
    const int tid = threadIdx.x;
    const int g   = blockIdx.x;

    const int b   = g >> 3;   // batch (= group id)
    const int mem = g & 7;    // member (K-slice & state-slice index)

    unsigned* slot = (unsigned*)ws;
    float* Pb = ws + WS_P;    // [2][NB][dst][src][KS]
    float* Zb = ws + WS_Zb;   // [2][NB][src][NO]

    __shared__ float vlds[BLK * CSTR];            // 116.7 KB CSR values
    __shared__ unsigned char ilds[BLK * CSTR];    // 29.2 KB CSR local col idx
    __shared__ float Alds[KS];                    // own A (local, no exchange)
    __shared__ float pred[KS];                    // own-dst partials
    __shared__ float zl[2][NO];

    const int lane = tid & 63, wid = tid >> 6;

    // ---- CSR build: thread t owns output rows 2t, 2t+1; cols [128*mem,+128) ----
    int cnt = 0, cnt0 = 0;
    {
        const int base = tid * CSTR;
        #pragma unroll
        for (int rr = 0; rr < 2; ++rr) {
            const int row = 2 * tid + rr;
            const float4* wp = (const float4*)(Whh   + row * NH + KS * mem);
            const float4* mp = (const float4*)(Wmask + row * NH + KS * mem);
            for (int c4 = 0; c4 < KS / 4; ++c4) {
                float4 wv = wp[c4], mv = mp[c4];
                if (mv.x != 0.f && cnt < CAP) { vlds[base+cnt] = wv.x * mv.x; ilds[base+cnt] = (unsigned char)(4*c4+0); ++cnt; }
                if (mv.y != 0.f && cnt < CAP) { vlds[base+cnt] = wv.y * mv.y; ilds[base+cnt] = (unsigned char)(4*c4+1); ++cnt; }
                if (mv.z != 0.f && cnt < CAP) { vlds[base+cnt] = wv.z * mv.z; ilds[base+cnt] = (unsigned char)(4*c4+2); ++cnt; }
                if (mv.w != 0.f && cnt < CAP) { vlds[base+cnt] = wv.w * mv.w; ilds[base+cnt] = (unsigned char)(4*c4+3); ++cnt; }
            }
            if (rr == 0) cnt0 = cnt;
        }
    }
    int mxT = cnt;
    #pragma unroll
    for (int d = 1; d < 64; d <<= 1) {
        int o = __shfl_xor(mxT, d, 64);
        mxT = o > mxT ? o : mxT;
    }

    // ---- state init: tid<128 owns neuron oi = 128*mem + tid, batch b ----
    const bool own = tid < KS;
    const int oi = KS * mem + tid;
    float h = 0.f, r = 0.f, u = 0.f, htr = 0.f, p = 0.f, sc = 0.f;
    float wih[8], wzv[NO];
    if (own) {
        h  = h0[b * NH + oi];
        r  = r0[b * NH + oi];
        u  = u0[b * NH + oi];
        p  = prel[oi];
        sc = scal[oi];
        #pragma unroll
        for (int k = 0; k < 8; ++k) wih[k] = Wih[oi * NI + k];
        #pragma unroll
        for (int o = 0; o < NO; ++o) wzv[o] = Whz[o * NH + oi];
        htr = tanhf(h);
        Alds[tid] = r * sc * htr;     // A for t=0 (LOCAL)
    }
    __syncthreads();                  // CSR + Alds ready

    const bool dofin = (mem == 0) && (wid == 4);   // z-finalizer role

    for (int t = 0; t < TSTEPS; ++t) {
        const int par = t & 1;

        // ---- x prefetch (cached; consumed in update) ----
        float4 xa = make_float4(0.f, 0.f, 0.f, 0.f), xb = xa;
        if (own) {
            const float4* xp = (const float4*)(x + (b * TSTEPS + t) * NI);
            xa = xp[0];
            xb = xp[1];
        }

        // ---- sparse GEMM (all local): partials for rows 2tid, 2tid+1 ----
        float a0 = 0.f, a1 = 0.f;
        {
            const int base = tid * CSTR;
            for (int s = 0; s < mxT; ++s) {
                if (s < cnt) {
                    float v  = vlds[base + s];
                    float av = Alds[ilds[base + s]];
                    if (s < cnt0) a0 = fmaf(v, av, a0);
                    else          a1 = fmaf(v, av, a1);
                }
            }
        }

        // ---- publish partials: wave == dst block (rows 128*wid..+128) ----
        if (wid == mem) {
            pred[2 * lane]     = a0;
            pred[2 * lane + 1] = a1;
        } else {
            float* pp = Pb + (((par * NB + b) * NMEM + wid) * NMEM + mem) * KS
                        + 2 * lane;
            astore64((u64*)pp, a0, a1);
        }

        // ---- the ONE barrier per step ----
        groupbar(slot, b, mem, (unsigned)(t + 1));

        // ---- z[t-1] finalize load (overlaps partial reads) ----
        float zv = 0.f;
        if (dofin && t >= 1)
            zv = aload1(Zb + ((par ^ 1) * NB + b) * (NMEM * NO) + lane);

        // ---- owner: gather 7 remote + 1 local partial, update state ----
        if (own) {
            float rec = pred[tid];
            const float* pb = Pb + (((par * NB + b) * NMEM + mem) * NMEM) * KS
                              + tid;
            #pragma unroll
            for (int s = 0; s < NMEM; ++s)
                if (s != mem) rec += aload1(pb + s * KS);

            float xv = fmaf(xa.x, wih[0], fmaf(xa.y, wih[1],
                       fmaf(xa.z, wih[2], xa.w * wih[3])));
            xv = fmaf(xb.x, wih[4], fmaf(xb.y, wih[5],
                 fmaf(xb.z, wih[6], fmaf(xb.w, wih[7], xv))));

            float drive = 0.5f * (1.0f + htr);
            float rn = r + ((p - r) / 0.2f - 10.0f * r * drive) * 0.001f;
            float un = u + ((p - u) / 1.5f + 10.0f * (1.0f - u) * drive) * 0.001f;
            float hn = h + ((-h + xv + rec) / 0.01f) * 0.001f;
            float htn = tanhf(hn);

            out[OFF_H + (b * TSTEPS + t) * NH + oi] = hn;
            out[OFF_R + (b * TSTEPS + t) * NH + oi] = rn;
            out[OFF_U + (b * TSTEPS + t) * NH + oi] = un;

            Alds[tid] = rn * sc * htn;      // A for t+1 (LOCAL)

            // z partial over own 128 neurons (waves 0,1)
            float zp[NO];
            #pragma unroll
            for (int o = 0; o < NO; ++o) zp[o] = htn * wzv[o];
            #pragma unroll
            for (int d = 1; d < 64; d <<= 1) {
                #pragma unroll
                for (int o = 0; o < NO; ++o) zp[o] += __shfl_xor(zp[o], d, 64);
            }
            if (lane == 0) {
                #pragma unroll
                for (int o = 0; o < NO; ++o) zl[wid][o] = zp[o];
            }

            h = hn; r = rn; u = un; htr = htn;
        }

        // ---- z[t-1] finalize: reduce over src (lane = src*8+o) ----
        if (dofin && t >= 1) {
            zv += __shfl_xor(zv, 8, 64);
            zv += __shfl_xor(zv, 16, 64);
            zv += __shfl_xor(zv, 32, 64);
            if (lane < NO)
                out[OFF_Z + (b * TSTEPS + (t - 1)) * NO + lane] = zv;
        }

        __syncthreads();   // Alds + zl ready (next gemm / Zbuf publish)

        // ---- publish this step's z partial (8 floats) ----
        if (tid < NO)
            astore(Zb + ((par * NB + b) * NMEM + mem) * NO + tid,
                   zl[0][tid] + zl[1][tid]);
        // (drained by next groupbar's leading syncthreads before the stamp)
    }

    // ---- epilogue: bar so all members' Zbuf[1] (t=999) are visible ----
    groupbar(slot, b, mem, (unsigned)(TSTEPS + 1));
    if (dofin) {
        float zv = aload1(Zb + (1 * NB + b) * (NMEM * NO) + lane);
        zv += __shfl_xor(zv, 8, 64);
        zv += __shfl_xor(zv, 16, 64);
        zv += __shfl_xor(zv, 32, 64);
        if (lane < NO)
            out[OFF_Z + (b * TSTEPS + 999) * NO + lane] = zv;
    }
}

extern "C" void kernel_launch(void* const* d_in, const int* in_sizes, int n_in,
                              void* d_out, int out_size, void* d_ws, size_t ws_size,
                              hipStream_t stream) {
    const float* x     = (const float*)d_in[0];
    const float* h0    = (const float*)d_in[1];
    const float* r0    = (const float*)d_in[2];
    const float* u0    = (const float*)d_in[3];
    const float* prel  = (const float*)d_in[4];
    const float* scal  = (const float*)d_in[5];
    const float* Wih   = (const float*)d_in[6];
    const float* Whh   = (const float*)d_in[7];
    const float* Wmask = (const float*)d_in[8];
    const float* Whz   = (const float*)d_in[9];
    float* out = (float*)d_out;
    float* ws  = (float*)d_ws;

    // Zero the 256 barrier slots (128B apart). Pbuf/Zbuf need no zeroing:
    // every read location is written earlier in the same launch.
    hipMemsetAsync(d_ws, 0, NWG * 128, stream);

    void* args[] = { &x, &h0, &r0, &u0, &prel, &scal,
                     &Wih, &Whh, &Wmask, &Whz, &out, &ws };
    hipLaunchCooperativeKernel((void*)rnn_stp_kernel, dim3(NWG), dim3(BLK),
                               args, 0, stream);
}

// Round 19
// 4909.173 us; speedup vs baseline: 1.6535x; 1.6535x over previous
//
#include <hip/hip_runtime.h>
#include <math.h>

// RNN with short-term plasticity: persistent cooperative kernel,
// 8 groups of 32 WGs; each WG pipelines TWO independent batch-contexts.
//
// Round 19: latency hiding WITHOUT co-residency. r11's 3.9us/step is a
// serial chain {poll RTT -> A-stage RTT -> compute -> publish -> stamp};
// r12/r13/r16/r18 all failed to shorten it. Here each WG interleaves two
// independent contexts (ctx0 = batches [4G,4G+2), ctx1 = [4G+2,4G+4)),
// same neurons, same w regs: phase(0,t) computes ctx0 while ctx1's
// stamps/data propagate, then phase(1,t). Every poll targets stamps set
// a FULL PHASE earlier -> first load passes (no straggler spin), and the
// flag RTT overlaps the other context's compute. Per-phase work halves
// (GB=2: 8KB stage, 128 FMA/thread). Stamp protocol per ctx = r11's
// proven one (poll-at-start, stamp-after-drain-sync; same double-buffer
// induction; skew bounded to one phase-pair). State regs are NAMED per
// ctx via template<int C> + reference params (rule #20). Whz in LDS to
// stay under the 128-VGPR wall (r12 trick).
//
#define NH 1024
#define NB 32
#define NI 8
#define NO 8
#define TSTEPS 1000

#define NWG 256
#define BLK 512
#define NG 8          // groups (4 batches each)
#define NM 32         // members per group
#define GB 2          // batches per context
#define NCTX 2

#define OFF_Z 0
#define OFF_H (NB * TSTEPS * NO)            // 256000
#define OFF_R (OFF_H + NB * TSTEPS * NH)    // 33024000
#define OFF_U (OFF_R + NB * TSTEPS * NH)    // 65792000

#define A_PAR  (NG * NH * GB)               // 16384 floats (one parity)
#define A_CSZ  (2 * A_PAR)
#define ZP_PAR (NG * GB * NO * NM)          // 4096
#define ZP_CSZ (2 * ZP_PAR)
// ws: slots[2][NWG] 128B lines (64KB) -> then A[ctx], then ZP[ctx]
#define WS_A   (NCTX * NWG * 32)
#define WS_ZP  (WS_A + NCTX * A_CSZ)

typedef unsigned long long u64;
typedef unsigned int u32;

__device__ __forceinline__ float2 aload2(const float* p) {
    u64 v = __hip_atomic_load((const u64*)p, __ATOMIC_RELAXED,
                              __HIP_MEMORY_SCOPE_AGENT);
    return __builtin_bit_cast(float2, v);
}
__device__ __forceinline__ float aload1(const float* p) {
    return __hip_atomic_load(p, __ATOMIC_RELAXED, __HIP_MEMORY_SCOPE_AGENT);
}
__device__ __forceinline__ void astore(float* p, float v) {
    __hip_atomic_store(p, v, __ATOMIC_RELAXED, __HIP_MEMORY_SCOPE_AGENT);
}
__device__ __forceinline__ u32 aload_u32(const u32* p) {
    return __hip_atomic_load(p, __ATOMIC_RELAXED, __HIP_MEMORY_SCOPE_AGENT);
}
__device__ __forceinline__ void astore_u32(u32* p, u32 v) {
    __hip_atomic_store(p, v, __ATOMIC_RELAXED, __HIP_MEMORY_SCOPE_AGENT);
}

template<int C>
__device__ __forceinline__ void do_phase(
    int t, int G, int m, int tid, int lane, int wid, int ks,
    const float* __restrict__ x, float* __restrict__ out,
    u32* __restrict__ slot, float* __restrict__ Abuf,
    float* __restrict__ ZPb,
    float2* __restrict__ atile, float* __restrict__ red,
    const float* __restrict__ wzlds,
    const float (&w)[2][32], const float (&wih)[8],
    float p, float sc,
    float& h, float& r, float& u, float& htr)
{
    const int par = t & 1;
    const bool own = tid < 64;
    const int ob = tid >> 5;
    const int on = tid & 31;
    const int oi = 32 * m + on;
    const int bglob = G * 4 + C * 2 + ob;

    // ---- poll ctx C stamps (set one full phase ago -> 1st load passes) ----
    if (tid < NM) {
        const u32* sp = &slot[(C * NWG + G * NM + tid) * 32];
        while (aload_u32(sp) < (u32)(t + 1)) __builtin_amdgcn_s_sleep(1);
    }
    __syncthreads();

    // ---- stage A_C[par] (8 KB): rows 2tid, 2tid+1 (float2 = both batches) ----
    {
        const float* Ag = Abuf + C * A_CSZ + par * A_PAR + G * (NH * GB);
        float2 s0 = aload2(Ag + 4 * tid);
        float2 s1 = aload2(Ag + 4 * tid + 2);
        const int r0i = 2 * tid;
        atile[r0i + (r0i >> 5)]     = s0;
        atile[r0i + 1 + (r0i >> 5)] = s1;
    }
    float4 xa = make_float4(0.f, 0.f, 0.f, 0.f), xb = xa;
    if (own) {
        const float4* xp = (const float4*)(x + (bglob * TSTEPS + t) * NI);
        xa = xp[0];
        xb = xp[1];
    }
    __syncthreads();

    // ---- GEMM: 32 j x 2 rows x 2 b; FULL unroll, static indices ----
    float a00 = 0.f, a01 = 0.f, a10 = 0.f, a11 = 0.f;
    {
        const float2* at2 = atile + 33 * ks;
        #pragma unroll
        for (int jj = 0; jj < 32; ++jj) {
            float2 a = at2[jj];
            a00 = fmaf(a.x, w[0][jj], a00);
            a01 = fmaf(a.y, w[0][jj], a01);
            a10 = fmaf(a.x, w[1][jj], a10);
            a11 = fmaf(a.y, w[1][jj], a11);
        }
    }
    #pragma unroll
    for (int mm = 16; mm <= 32; mm <<= 1) {
        a00 += __shfl_xor(a00, mm, 64);
        a01 += __shfl_xor(a01, mm, 64);
        a10 += __shfl_xor(a10, mm, 64);
        a11 += __shfl_xor(a11, mm, 64);
    }
    if (lane < 16) {
        float* rp = red + (wid * 16 + lane) * 5;
        rp[0] = a00; rp[1] = a01; rp[2] = a10; rp[3] = a11;
    }

    // ---- z[t-1] finalize load (issued early, overlaps red-sync) ----
    const int mr = (C == 0) ? m : (m - 16);
    const bool fin = (wid == 4) && ((C == 0) ? (m < 16) : (m >= 16)) && (t >= 1);
    float zv = 0.f;
    if (fin && lane < NM)
        zv = aload1(ZPb + C * ZP_CSZ + (par ^ 1) * ZP_PAR + G * (GB * NO * NM)
                    + ((mr >> 3) & 1) * (NO * NM) + (mr & 7) * NM + lane);
    __syncthreads();   // red ready

    // ---- owner: combine partials, update state, publish, z-partial ----
    if (own) {
        float rec = 0.f;
        #pragma unroll
        for (int wv = 0; wv < 8; ++wv)
            rec += red[(wv * 16 + (on & 15)) * 5 + (on >> 4) * 2 + ob];

        float xv = fmaf(xa.x, wih[0], fmaf(xa.y, wih[1],
                   fmaf(xa.z, wih[2], xa.w * wih[3])));
        xv = fmaf(xb.x, wih[4], fmaf(xb.y, wih[5],
             fmaf(xb.z, wih[6], fmaf(xb.w, wih[7], xv))));

        float drive = 0.5f * (1.0f + htr);
        float rn = r + ((p - r) / 0.2f - 10.0f * r * drive) * 0.001f;
        float un = u + ((p - u) / 1.5f + 10.0f * (1.0f - u) * drive) * 0.001f;
        float hn = h + ((-h + xv + rec) / 0.01f) * 0.001f;
        float htn = tanhf(hn);

        out[OFF_H + (bglob * TSTEPS + t) * NH + oi] = hn;
        out[OFF_R + (bglob * TSTEPS + t) * NH + oi] = rn;
        out[OFF_U + (bglob * TSTEPS + t) * NH + oi] = un;

        astore(&Abuf[C * A_CSZ + (par ^ 1) * A_PAR + G * (NH * GB)
                     + oi * GB + ob], rn * sc * htn);

        // z partial: reduce htn*Whz over the 32 on-lanes (owners are wave 0)
        float zp[NO];
        #pragma unroll
        for (int o = 0; o < NO; ++o) zp[o] = htn * wzlds[on * NO + o];
        #pragma unroll
        for (int d = 1; d <= 16; d <<= 1) {
            #pragma unroll
            for (int o = 0; o < NO; ++o) zp[o] += __shfl_xor(zp[o], d, 64);
        }
        if (on == 0) {   // lanes 0 (ob=0) and 32 (ob=1)
            float* zpp = ZPb + C * ZP_CSZ + par * ZP_PAR + G * (GB * NO * NM)
                         + ob * (NO * NM) + m;
            #pragma unroll
            for (int o = 0; o < NO; ++o) astore(zpp + o * NM, zp[o]);
        }

        h = hn; r = rn; u = un; htr = htn;
    }

    // ---- z[t-1] finalize reduce + write ----
    if (fin) {
        zv += __shfl_xor(zv, 1, 64);
        zv += __shfl_xor(zv, 2, 64);
        zv += __shfl_xor(zv, 4, 64);
        zv += __shfl_xor(zv, 8, 64);
        zv += __shfl_xor(zv, 16, 64);
        if (lane == 0) {
            const int bfin = G * 4 + C * 2 + ((mr >> 3) & 1);
            out[OFF_Z + (bfin * TSTEPS + (t - 1)) * NO + (mr & 7)] = zv;
        }
    }

    __syncthreads();   // drain all agent stores (vmcnt) before the stamp
    if (tid == 0)
        astore_u32(&slot[(C * NWG + G * NM + m) * 32], (u32)(t + 2));
}

__global__ __launch_bounds__(BLK, 2) void rnn_stp_kernel(
    const float* __restrict__ x,     // [32][1000][8]
    const float* __restrict__ h0,    // [32][1024]
    const float* __restrict__ r0,    // [32][1024]
    const float* __restrict__ u0,    // [32][1024]
    const float* __restrict__ prel,  // [1024]
    const float* __restrict__ scal,  // [1024]
    const float* __restrict__ Wih,   // [1024][8]
    const float* __restrict__ Whh,   // [1024][1024]
    const float* __restrict__ Wmask, // [1024][1024]
    const float* __restrict__ Whz,   // [8][1024]
    float* __restrict__ out,
    float* __restrict__ ws)
{
    const int tid = threadIdx.x;
    const int g   = blockIdx.x;

    const int G = g & 7;
    const int m = g >> 3;

    u32* slot   = (u32*)ws;
    float* Abuf = ws + WS_A;
    float* ZPb  = ws + WS_ZP;

    const int ib = 32 * m;

    __shared__ float2 atile[NH + NM];          // shared by both phases (sync'd)
    __shared__ float  red[8 * 16 * 5];
    __shared__ float  wzlds[NM * NO];          // [on][o]

    const int lane = tid & 63, wid = tid >> 6;
    const int ks = tid >> 4;
    const int il = tid & 15;

    if (tid < NM * NO)
        wzlds[tid] = Whz[(tid & 7) * NH + ib + (tid >> 3)];

    // Masked weights (fully static indexing -> register-resident, rule #20)
    float w[2][32];
    #pragma unroll
    for (int nn = 0; nn < 2; ++nn) {
        const int row = ib + il + 16 * nn;
        const float* wp = Whh   + row * NH + 32 * ks;
        const float* mp = Wmask + row * NH + 32 * ks;
        #pragma unroll
        for (int jj = 0; jj < 32; ++jj) w[nn][jj] = wp[jj] * mp[jj];
    }

    // ---- owner init (both contexts) ----
    const bool own = tid < 64;
    const int ob = tid >> 5;
    const int on = tid & 31;
    const int oi = ib + on;
    float p = 0.f, sc = 0.f;
    float wih[8] = {0.f, 0.f, 0.f, 0.f, 0.f, 0.f, 0.f, 0.f};
    float hA = 0.f, rA = 0.f, uA = 0.f, htA = 0.f;
    float hB = 0.f, rB = 0.f, uB = 0.f, htB = 0.f;
    if (own) {
        p  = prel[oi];
        sc = scal[oi];
        #pragma unroll
        for (int k = 0; k < 8; ++k) wih[k] = Wih[oi * NI + k];
        const int bgA = G * 4 + ob, bgB = G * 4 + 2 + ob;
        hA = h0[bgA * NH + oi]; rA = r0[bgA * NH + oi]; uA = u0[bgA * NH + oi];
        htA = tanhf(hA);
        astore(&Abuf[0 * A_CSZ + G * (NH * GB) + oi * GB + ob], rA * sc * htA);
        hB = h0[bgB * NH + oi]; rB = r0[bgB * NH + oi]; uB = u0[bgB * NH + oi];
        htB = tanhf(hB);
        astore(&Abuf[1 * A_CSZ + G * (NH * GB) + oi * GB + ob], rB * sc * htB);
    }
    __syncthreads();   // drain A(0) publishes
    if (tid == 0) {
        astore_u32(&slot[(0 * NWG + G * NM + m) * 32], 1u);
        astore_u32(&slot[(1 * NWG + G * NM + m) * 32], 1u);
    }

    for (int t = 0; t < TSTEPS; ++t) {
        do_phase<0>(t, G, m, tid, lane, wid, ks, x, out, slot, Abuf, ZPb,
                    atile, red, wzlds, w, wih, p, sc, hA, rA, uA, htA);
        do_phase<1>(t, G, m, tid, lane, wid, ks, x, out, slot, Abuf, ZPb,
                    atile, red, wzlds, w, wih, p, sc, hB, rB, uB, htB);
    }

    // ---- epilogue: wait for all members' final publishes, z[999] ----
    if (tid < NM) {
        const u32* sp0 = &slot[(0 * NWG + G * NM + tid) * 32];
        while (aload_u32(sp0) < (u32)(TSTEPS + 1)) __builtin_amdgcn_s_sleep(1);
        const u32* sp1 = &slot[(1 * NWG + G * NM + tid) * 32];
        while (aload_u32(sp1) < (u32)(TSTEPS + 1)) __builtin_amdgcn_s_sleep(1);
    }
    __syncthreads();
    if (wid == 4) {
        const int Ce = (m < 16) ? 0 : 1;
        const int mr = (m < 16) ? m : (m - 16);
        float zv = 0.f;
        if (lane < NM)
            zv = aload1(ZPb + Ce * ZP_CSZ + 1 * ZP_PAR + G * (GB * NO * NM)
                        + ((mr >> 3) & 1) * (NO * NM) + (mr & 7) * NM + lane);
        zv += __shfl_xor(zv, 1, 64);
        zv += __shfl_xor(zv, 2, 64);
        zv += __shfl_xor(zv, 4, 64);
        zv += __shfl_xor(zv, 8, 64);
        zv += __shfl_xor(zv, 16, 64);
        if (lane == 0) {
            const int bfin = G * 4 + Ce * 2 + ((mr >> 3) & 1);
            out[OFF_Z + (bfin * TSTEPS + 999) * NO + (mr & 7)] = zv;
        }
    }
}

extern "C" void kernel_launch(void* const* d_in, const int* in_sizes, int n_in,
                              void* d_out, int out_size, void* d_ws, size_t ws_size,
                              hipStream_t stream) {
    const float* x     = (const float*)d_in[0];
    const float* h0    = (const float*)d_in[1];
    const float* r0    = (const float*)d_in[2];
    const float* u0    = (const float*)d_in[3];
    const float* prel  = (const float*)d_in[4];
    const float* scal  = (const float*)d_in[5];
    const float* Wih   = (const float*)d_in[6];
    const float* Whh   = (const float*)d_in[7];
    const float* Wmask = (const float*)d_in[8];
    const float* Whz   = (const float*)d_in[9];
    float* out = (float*)d_out;
    float* ws  = (float*)d_ws;

    // Zero both contexts' stamp slot regions (2 x 256 x 128B).
    hipMemsetAsync(d_ws, 0, NCTX * NWG * 128, stream);

    void* args[] = { &x, &h0, &r0, &u0, &prel, &scal,
                     &Wih, &Whh, &Wmask, &Whz, &out, &ws };
    hipLaunchCooperativeKernel((void*)rnn_stp_kernel, dim3(NWG), dim3(BLK),
                               args, 0, stream);
}